// Round 1
// baseline (86.210 us; speedup 1.0000x reference)
//
#include <hip/hip_runtime.h>
#include <cstdint>

// MMCL loss: per-row top-K hard negatives.
// M=4096 rows, N=13000 cols fp32; K = int(0.01*(N-1)) = 129.
// loss_row = 5*(1-pos)^2 + mean_{topK negatives}((1+v)^2); output = mean over rows.

constexpr int M_ROWS = 4096;
constexpr int N_COLS = 13000;
constexpr int KSEL   = 129;     // int(0.01 * 12999)
constexpr int CAP    = 1024;    // candidate buffer capacity
constexpr float DELTA_C = 5.0f;
constexpr int BLOCK  = 256;

// monotone float -> uint32 key (larger float => larger key)
__device__ __forceinline__ uint32_t f2key(float f) {
    uint32_t u = __float_as_uint(f);
    return u ^ ((u & 0x80000000u) ? 0xFFFFFFFFu : 0x80000000u);
}
__device__ __forceinline__ float key2f(uint32_t k) {
    uint32_t u = (k & 0x80000000u) ? (k ^ 0x80000000u) : ~k;
    return __uint_as_float(u);
}

__global__ __launch_bounds__(BLOCK) void row_loss_kernel(
    const float* __restrict__ inputs,
    const int*   __restrict__ targets,
    float*       __restrict__ row_loss)
{
    __shared__ float cand[CAP];
    __shared__ int   s_int[BLOCK];
    __shared__ float s_flt[BLOCK];
    __shared__ int   s_idx;
    __shared__ float s_T;

    const int row = blockIdx.x;
    const int tid = threadIdx.x;
    const float* rp = inputs + (size_t)row * N_COLS;
    const int pos = targets[row];
    const float pos_v = rp[pos];

    // Exact selection of candidate threshold region.
    // Common case: t = 2.0 gives K <= cnt <= CAP in ONE global pass.
    // Fallback (never for N(0,1) data, kept for exactness): bisection on the
    // sortable-key space, with a tie-collapse path.
    uint32_t keyA = 0u;           // cnt(keyA) > CAP side
    uint32_t keyB = 0xFFFFFFFFu;  // cnt(keyB) < K side
    float t = 2.0f;
    bool collapsed = false;       // K-th largest known exactly (== Tval)
    float Tval = 0.0f;
    int total = 0;

    for (int iter = 0; iter < 64; ++iter) {
        if (tid == 0) s_idx = 0;
        __syncthreads();
        int my = 0;
        for (int j4 = tid; j4 < N_COLS / 4; j4 += BLOCK) {
            const float4 v = reinterpret_cast<const float4*>(rp)[j4];
            const int base = j4 * 4;
            const float xs[4] = {v.x, v.y, v.z, v.w};
            #pragma unroll
            for (int e = 0; e < 4; ++e) {
                const float x = xs[e];
                if (x > t && (base + e) != pos) {
                    ++my;
                    const int slot = atomicAdd(&s_idx, 1);
                    if (slot < CAP) cand[slot] = x;
                }
            }
        }
        s_int[tid] = my;
        __syncthreads();
        for (int off = BLOCK / 2; off > 0; off >>= 1) {
            if (tid < off) s_int[tid] += s_int[tid + off];
            __syncthreads();
        }
        const int cnt = s_int[0];
        __syncthreads();   // protect s_int before next-iteration reuse

        if (collapsed || (cnt >= KSEL && cnt <= CAP)) { total = cnt; break; }

        const uint32_t kt = f2key(t);
        if (cnt > CAP) keyA = kt; else keyB = kt;
        if (keyB - keyA <= 1u) {
            // No float strictly between brackets: the K-th largest value is
            // exactly key2f(keyB). Re-collect strictly-greater set (< K elems).
            Tval = key2f(keyB);
            t = Tval;
            collapsed = true;
            continue;
        }
        t = key2f(keyA + (keyB - keyA) / 2u);
    }

    const int C = total < CAP ? total : CAP;

    // Find T = K-th largest among candidates (all values > T are candidates).
    float T;
    if (collapsed) {
        T = Tval;   // candidates are exactly {v > T}, count < K
    } else {
        for (int c = tid; c < C; c += BLOCK) {
            const float x = cand[c];
            int g = 0, ge = 0;
            for (int j = 0; j < C; ++j) {
                const float y = cand[j];   // broadcast read, conflict-free
                g  += (y > x);
                ge += (y >= x);
            }
            if (g < KSEL && ge >= KSEL) s_T = x;  // unique value; benign race
        }
        __syncthreads();
        T = s_T;
    }

    // Sum f(v) = (1+v)^2 over values strictly greater than T, then pad with
    // (K - count) copies of f(T) (exact under ties, matches lax.top_k).
    float s = 0.0f;
    int g = 0;
    for (int c = tid; c < C; c += BLOCK) {
        const float x = cand[c];
        if (x > T) { const float u = 1.0f + x; s += u * u; ++g; }
    }
    s_flt[tid] = s;
    s_int[tid] = g;
    __syncthreads();
    for (int off = BLOCK / 2; off > 0; off >>= 1) {
        if (tid < off) { s_flt[tid] += s_flt[tid + off]; s_int[tid] += s_int[tid + off]; }
        __syncthreads();
    }
    if (tid == 0) {
        const float uT = 1.0f + T;
        const float neg = (s_flt[0] + (float)(KSEL - s_int[0]) * uT * uT) / (float)KSEL;
        const float d = 1.0f - pos_v;
        row_loss[row] = DELTA_C * d * d + neg;
    }
}

__global__ __launch_bounds__(1024) void reduce_kernel(
    const float* __restrict__ row_loss, float* __restrict__ out)
{
    __shared__ float s[1024];
    float acc = 0.0f;
    for (int i = threadIdx.x; i < M_ROWS; i += 1024) acc += row_loss[i];
    s[threadIdx.x] = acc;
    __syncthreads();
    for (int off = 512; off > 0; off >>= 1) {
        if (threadIdx.x < off) s[threadIdx.x] += s[threadIdx.x + off];
        __syncthreads();
    }
    if (threadIdx.x == 0) out[0] = s[0] / (float)M_ROWS;
}

extern "C" void kernel_launch(void* const* d_in, const int* in_sizes, int n_in,
                              void* d_out, int out_size, void* d_ws, size_t ws_size,
                              hipStream_t stream) {
    const float* inputs  = (const float*)d_in[0];
    // d_in[1] = targets_ (unused by reference), d_in[3] = GT_MC (unused)
    const int*   targets = (const int*)d_in[2];
    float* row_loss = (float*)d_ws;   // 4096 floats = 16 KB scratch

    row_loss_kernel<<<M_ROWS, BLOCK, 0, stream>>>(inputs, targets, row_loss);
    reduce_kernel<<<1, 1024, 0, stream>>>(row_loss, (float*)d_out);
}

// Round 2
// 60.508 us; speedup vs baseline: 1.4248x; 1.4248x over previous
//
#include <hip/hip_runtime.h>
#include <cstdint>

// MMCL loss: per-row top-K hard negatives.
// M=4096 rows, N=13000 cols fp32; K = int(0.01*(N-1)) = 129.
// loss_row = 5*(1-pos)^2 + mean_{topK negatives}((1+v)^2); output = mean over rows.
//
// Strategy: one 256-thread block per row. Single streaming pass compacts all
// values > t0=2.0 (expected ~296 for N(0,1); per-wave register-counter
// compaction via ballot, no LDS atomics) into per-wave LDS segments. Then an
// 8-pass 4-bit radix select finds the exact K-th largest value T; final sum is
// sum_{v>T} (1+v)^2 + (K - cnt)*(1+T)^2 (exact under ties, == lax.top_k sum).
// Pathological distributions fall back to exact threshold bisection in
// sortable-key space (never triggered for this data; kept for correctness).

constexpr int M_ROWS = 4096;
constexpr int N_COLS = 13000;
constexpr int N4     = N_COLS / 4;    // 3250 float4s, 13000 % 4 == 0
constexpr int KSEL   = 129;           // int(0.01 * 12999)
constexpr int BLOCK  = 256;
constexpr int NWAVE  = BLOCK / 64;    // 4
constexpr int WCAP   = 320;           // per-wave candidate cap (~74 expected, 29 sigma)
constexpr float DELTA_C = 5.0f;
constexpr float T0   = 2.0f;

// monotone float -> uint32 key (larger float => larger key)
__device__ __forceinline__ uint32_t f2key(float f) {
    uint32_t u = __float_as_uint(f);
    return u ^ ((u & 0x80000000u) ? 0xFFFFFFFFu : 0x80000000u);
}
__device__ __forceinline__ float key2f(uint32_t k) {
    uint32_t u = (k & 0x80000000u) ? (k ^ 0x80000000u) : ~k;
    return __uint_as_float(u);
}

__global__ __launch_bounds__(BLOCK) void row_loss_kernel(
    const float* __restrict__ inputs,
    const int*   __restrict__ targets,
    float*       __restrict__ row_loss)
{
    __shared__ float cand[NWAVE * WCAP];   // per-wave segments
    __shared__ int   s_wcnt[NWAVE];
    __shared__ int   s_hist[16];
    __shared__ float s_fpart[NWAVE];
    __shared__ int   s_ipart[NWAVE];
    __shared__ int   s_bucket;
    __shared__ int   s_need;

    const int row  = blockIdx.x;
    const int tid  = threadIdx.x;
    const int wid  = tid >> 6;
    const int lane = tid & 63;
    const float* rp = inputs + (size_t)row * N_COLS;
    const int pos = targets[row];
    const float pos_v = rp[pos];

    // ---- exact candidate collection (common case: one pass at t = 2.0) ----
    uint32_t keyA = 0u;           // bracket: too-many side
    uint32_t keyB = 0xFFFFFFFFu;  // bracket: too-few side
    float t = T0;
    bool collapsed = false;       // K-th largest value known exactly (Tval)
    float Tval = 0.0f;

    for (int iter = 0; iter < 64; ++iter) {
        int wcnt = 0;             // wave-uniform running count (register)
        for (int j4 = tid; j4 < N4; j4 += BLOCK) {
            const float4 v = reinterpret_cast<const float4*>(rp)[j4];
            const int base = j4 * 4;
            const float xs[4] = {v.x, v.y, v.z, v.w};
            #pragma unroll
            for (int e = 0; e < 4; ++e) {
                const float x = xs[e];
                const bool pred = (x > t) && ((base + e) != pos);
                const uint64_t m = __ballot(pred);
                if (pred) {
                    const int slot = wcnt + (int)__popcll(m & ((1ull << lane) - 1ull));
                    if (slot < WCAP) cand[wid * WCAP + slot] = x;
                }
                wcnt += (int)__popcll(m);
            }
        }
        if (lane == 0) s_wcnt[wid] = wcnt;
        __syncthreads();
        const int c0 = s_wcnt[0], c1 = s_wcnt[1], c2 = s_wcnt[2], c3 = s_wcnt[3];
        __syncthreads();
        const int total = c0 + c1 + c2 + c3;
        const bool ovf = (c0 > WCAP) | (c1 > WCAP) | (c2 > WCAP) | (c3 > WCAP);

        if (collapsed || (!ovf && total >= KSEL)) break;

        const uint32_t kt = f2key(t);
        if (ovf) keyA = kt; else keyB = kt;
        if (keyB - keyA <= 1u) {
            // no representable float strictly between brackets:
            // #{x > key2f(keyB)} < K <= #{x >= key2f(keyB)}  =>  T is exact
            Tval = key2f(keyB);
            t = Tval;
            collapsed = true;
            continue;
        }
        t = key2f(keyA + (keyB - keyA) / 2u);
    }

    // ---- exact K-th largest via 8-pass 4-bit radix select over candidates ----
    float T;
    if (collapsed) {
        T = Tval;   // candidates are exactly {v > T}, count < K
    } else {
        uint32_t hi = 0;   // chosen high bits (low bits zero)
        int need = KSEL;
        for (int shift = 28; shift >= 0; shift -= 4) {
            if (tid < 16) s_hist[tid] = 0;
            __syncthreads();
            const uint32_t maskHigh = (uint32_t)(0xFFFFFFFFull << (shift + 4));
            {   // wave w scans its own segment
                const int cw = s_wcnt[wid];
                const float* seg = cand + wid * WCAP;
                for (int c = lane; c < cw; c += 64) {
                    const uint32_t k = f2key(seg[c]);
                    if ((k & maskHigh) == hi)
                        atomicAdd(&s_hist[(k >> shift) & 15], 1);
                }
            }
            __syncthreads();
            if (tid == 0) {
                int cum = 0, b = 15;
                for (; b > 0; --b) {
                    const int h = s_hist[b];
                    if (cum + h >= need) break;
                    cum += h;
                }
                s_bucket = b;
                s_need = need - cum;
            }
            __syncthreads();
            hi |= ((uint32_t)s_bucket) << shift;
            need = s_need;
        }
        T = key2f(hi);
    }

    // ---- sum f(v)=(1+v)^2 over v > T, pad with (K-cnt) copies of f(T) ----
    float s = 0.0f;
    int g = 0;
    {
        const int cw = s_wcnt[wid] < WCAP ? s_wcnt[wid] : WCAP;
        const float* seg = cand + wid * WCAP;
        for (int c = lane; c < cw; c += 64) {
            const float x = seg[c];
            if (x > T) { const float u = 1.0f + x; s += u * u; ++g; }
        }
    }
    #pragma unroll
    for (int off = 32; off > 0; off >>= 1) {
        s += __shfl_down(s, off);
        g += __shfl_down(g, off);
    }
    if (lane == 0) { s_fpart[wid] = s; s_ipart[wid] = g; }
    __syncthreads();
    if (tid == 0) {
        float ss = s_fpart[0] + s_fpart[1] + s_fpart[2] + s_fpart[3];
        int   gg = s_ipart[0] + s_ipart[1] + s_ipart[2] + s_ipart[3];
        const float uT = 1.0f + T;
        const float neg = (ss + (float)(KSEL - gg) * uT * uT) / (float)KSEL;
        const float d = 1.0f - pos_v;
        row_loss[row] = DELTA_C * d * d + neg;
    }
}

__global__ __launch_bounds__(1024) void reduce_kernel(
    const float* __restrict__ row_loss, float* __restrict__ out)
{
    __shared__ float s[1024];
    float acc = 0.0f;
    for (int i = threadIdx.x; i < M_ROWS; i += 1024) acc += row_loss[i];
    s[threadIdx.x] = acc;
    __syncthreads();
    for (int off = 512; off > 0; off >>= 1) {
        if (threadIdx.x < off) s[threadIdx.x] += s[threadIdx.x + off];
        __syncthreads();
    }
    if (threadIdx.x == 0) out[0] = s[0] / (float)M_ROWS;
}

extern "C" void kernel_launch(void* const* d_in, const int* in_sizes, int n_in,
                              void* d_out, int out_size, void* d_ws, size_t ws_size,
                              hipStream_t stream) {
    const float* inputs  = (const float*)d_in[0];
    // d_in[1] = targets_ (unused by reference), d_in[3] = GT_MC (unused)
    const int*   targets = (const int*)d_in[2];
    float* row_loss = (float*)d_ws;   // 4096 floats = 16 KB scratch

    row_loss_kernel<<<M_ROWS, BLOCK, 0, stream>>>(inputs, targets, row_loss);
    reduce_kernel<<<1, 1024, 0, stream>>>(row_loss, (float*)d_out);
}